// Round 14
// baseline (815.047 us; speedup 1.0000x reference)
//
#include <hip/hip_runtime.h>
#include <hip/hip_bf16.h>
#include <cstdint>

#define DEVINL __device__ __forceinline__

using f32x4  = __attribute__((ext_vector_type(4))) float;
using short8 = __attribute__((ext_vector_type(8))) short;
using short4v = __attribute__((ext_vector_type(4))) short;

DEVINL float bf2f(__hip_bfloat16 h){ return __bfloat162float(h); }
DEVINL __hip_bfloat16 f2bf(float f){ return __float2bfloat16(f); }
DEVINL short bfbits(float f){ __hip_bfloat16 h = __float2bfloat16(f); short s; __builtin_memcpy(&s, &h, 2); return s; }
DEVINL float sb2f(short s){ uint32_t u = ((uint32_t)(uint16_t)s) << 16; float f; __builtin_memcpy(&f, &u, 4); return f; }

DEVINL void gl_lds16(const void* g, void* l){
  __builtin_amdgcn_global_load_lds((const __attribute__((address_space(1))) void*)g,
                                   (__attribute__((address_space(3))) void*)l, 16, 0, 0);
}

// ---------------- weight transpose + f32->bf16 cast: dst[C][R] = src[R][C] ----------------
__global__ __launch_bounds__(256) void wtrans(const float* __restrict__ src,
                                              __hip_bfloat16* __restrict__ dst,
                                              int R, int C){
  __shared__ float tile[32][33];
  const int tr0 = blockIdx.y*32, tc0 = blockIdx.x*32;
  const int t = threadIdx.x;
  const int lr = t >> 3, lc = (t & 7) * 4;
  float4 v = *(const float4*)(src + (size_t)(tr0+lr)*C + tc0 + lc);
  tile[lr][lc] = v.x; tile[lr][lc+1] = v.y; tile[lr][lc+2] = v.z; tile[lr][lc+3] = v.w;
  __syncthreads();
  short4v o;
  o[0] = bfbits(tile[lc+0][lr]);
  o[1] = bfbits(tile[lc+1][lr]);
  o[2] = bfbits(tile[lc+2][lr]);
  o[3] = bfbits(tile[lc+3][lr]);
  *(short4v*)(dst + (size_t)(tc0+lr)*R + tr0 + lc) = o;
}

// ---------------- LayerNorm (C=2048), one row per block, bf16 out ----------------
__global__ __launch_bounds__(256) void ln_k(const float* __restrict__ x,
                                            const float* __restrict__ w,
                                            const float* __restrict__ bia,
                                            __hip_bfloat16* __restrict__ out){
  const int row = blockIdx.x, t = threadIdx.x;
  const float* xr = x + (size_t)row*2048;
  float4 v0 = *(const float4*)(xr + t*4);
  float4 v1 = *(const float4*)(xr + 1024 + t*4);
  float s  = v0.x+v0.y+v0.z+v0.w + v1.x+v1.y+v1.z+v1.w;
  float ss = v0.x*v0.x+v0.y*v0.y+v0.z*v0.z+v0.w*v0.w
           + v1.x*v1.x+v1.y*v1.y+v1.z*v1.z+v1.w*v1.w;
  #pragma unroll
  for (int o=1;o<64;o<<=1){ s += __shfl_xor(s,o); ss += __shfl_xor(ss,o); }
  __shared__ float red[8];
  const int wv = t>>6, ln = t&63;
  if (ln==0){ red[wv]=s; red[4+wv]=ss; }
  __syncthreads();
  s = red[0]+red[1]+red[2]+red[3]; ss = red[4]+red[5]+red[6]+red[7];
  const float mu = s*(1.f/2048.f);
  const float inv = rsqrtf(ss*(1.f/2048.f) - mu*mu + 1e-5f);
  {
    float4 wv4 = *(const float4*)(w + t*4);
    float4 bv4 = *(const float4*)(bia + t*4);
    short4v o;
    o[0]=bfbits((v0.x-mu)*inv*wv4.x + bv4.x);
    o[1]=bfbits((v0.y-mu)*inv*wv4.y + bv4.y);
    o[2]=bfbits((v0.z-mu)*inv*wv4.z + bv4.z);
    o[3]=bfbits((v0.w-mu)*inv*wv4.w + bv4.w);
    *(short4v*)(out + (size_t)row*2048 + t*4) = o;
  }
  {
    float4 wv4 = *(const float4*)(w + 1024 + t*4);
    float4 bv4 = *(const float4*)(bia + 1024 + t*4);
    short4v o;
    o[0]=bfbits((v1.x-mu)*inv*wv4.x + bv4.x);
    o[1]=bfbits((v1.y-mu)*inv*wv4.y + bv4.y);
    o[2]=bfbits((v1.z-mu)*inv*wv4.z + bv4.z);
    o[3]=bfbits((v1.w-mu)*inv*wv4.w + bv4.w);
    *(short4v*)(out + (size_t)row*2048 + 1024 + t*4) = o;
  }
}

// ====== quad-buffered GEMM (r10-proven): C[M,N]=A[M,K]*Bt[N,K]^T, BM x 256, BK=32 ======
// EPI 4: bf16   2: silu->bf16   3: *emul->bf16 (in-place ok)   1: f32 + resid (in-place ok)
template<int EPI, int BM>
__global__ __launch_bounds__(512, 2) void gemmp(
    const __hip_bfloat16* __restrict__ A,
    const __hip_bfloat16* __restrict__ Bt,
    __hip_bfloat16* __restrict__ Cb,
    float* __restrict__ Cf,
    const float* __restrict__ resid,
    const __hip_bfloat16* __restrict__ emul,
    int M, int N, int K, int NTN)
{
  constexpr int MF    = BM/32;
  constexpr int LA    = BM/128;
  constexpr int ABY   = BM*64;
  constexpr int TILEB = ABY + 16384;
  extern __shared__ char smem[];
  const int tid = threadIdx.x, lane = tid & 63, wave = tid >> 6;
  const int l15 = lane & 15, l4 = lane >> 4;
  const int wm = wave >> 2, wn = wave & 3;

  const int nwg = gridDim.x;
  const int id  = blockIdx.x;
  const int swz = (id & 7) * (nwg >> 3) + (id >> 3);
  const int by = swz / NTN, bx = swz % NTN;
  const int row0 = by * BM, col0 = bx * 256;

  const __hip_bfloat16* srcA[LA]; int dstA[LA];
  #pragma unroll
  for (int g = 0; g < LA; ++g){
    const int c = g*512 + tid, r = c >> 2, s = c & 3;
    const int kbyte = (s*16) ^ (((r >> 1) & 3) << 4);
    srcA[g] = A + (size_t)(row0 + r)*K + (kbyte >> 1);
    dstA[g] = c*16;
  }
  const __hip_bfloat16* srcB[2]; int dstB[2];
  #pragma unroll
  for (int g = 0; g < 2; ++g){
    const int c = g*512 + tid, r = c >> 2, s = c & 3;
    const int kbyte = (s*16) ^ (((r >> 1) & 3) << 4);
    srcB[g] = Bt + (size_t)(col0 + r)*K + (kbyte >> 1);
    dstB[g] = c*16;
  }
  auto STAGE = [&](int bi, int kt){
    char* base = smem + bi*TILEB;
    #pragma unroll
    for (int g = 0; g < LA; ++g) gl_lds16(srcA[g] + kt*32, base + dstA[g]);
    #pragma unroll
    for (int g = 0; g < 2; ++g)  gl_lds16(srcB[g] + kt*32, base + ABY + dstB[g]);
  };

  const int rmask = ((l15 >> 1) & 3) << 4;
  int offA[MF], offB[4];
  #pragma unroll
  for (int m = 0; m < MF; ++m){
    const int r = wm*(BM/2) + m*16 + l15;
    offA[m] = r*64 + ((l4*16) ^ rmask);
  }
  #pragma unroll
  for (int n = 0; n < 4; ++n){
    const int r = wn*64 + n*16 + l15;
    offB[n] = r*64 + ((l4*16) ^ rmask);
  }

  f32x4 acc[MF][4] = {};
  const int NT = K >> 5;

  STAGE(0, 0); STAGE(1, 1); STAGE(2, 2);
  __builtin_amdgcn_sched_barrier(0);
  if constexpr (BM == 256) asm volatile("s_waitcnt vmcnt(8)" ::: "memory");
  else                     asm volatile("s_waitcnt vmcnt(6)" ::: "memory");
  __builtin_amdgcn_s_barrier();
  __builtin_amdgcn_sched_barrier(0);

  for (int t = 0; t < NT; ++t){
    const char* base = smem + (t & 3)*TILEB;
    if (t + 3 < NT) STAGE((t + 3) & 3, t + 3);
    short8 a[MF], b[4];
    #pragma unroll
    for (int m = 0; m < MF; ++m) a[m] = *(const short8*)(base + offA[m]);
    #pragma unroll
    for (int n = 0; n < 4; ++n)  b[n] = *(const short8*)(base + ABY + offB[n]);
    __builtin_amdgcn_s_setprio(1);
    #pragma unroll
    for (int m = 0; m < MF; ++m)
      #pragma unroll
      for (int n = 0; n < 4; ++n)
        acc[m][n] = __builtin_amdgcn_mfma_f32_16x16x32_bf16(a[m], b[n], acc[m][n], 0, 0, 0);
    __builtin_amdgcn_s_setprio(0);
    if (t + 3 < NT){
      if constexpr (BM == 256) asm volatile("s_waitcnt vmcnt(8)" ::: "memory");
      else                     asm volatile("s_waitcnt vmcnt(6)" ::: "memory");
    } else if (t + 2 < NT){
      if constexpr (BM == 256) asm volatile("s_waitcnt vmcnt(4)" ::: "memory");
      else                     asm volatile("s_waitcnt vmcnt(3)" ::: "memory");
    } else {
      asm volatile("s_waitcnt vmcnt(0)" ::: "memory");
    }
    __builtin_amdgcn_s_barrier();
    __builtin_amdgcn_sched_barrier(0);
  }

  #pragma unroll
  for (int m = 0; m < MF; ++m){
    const int r0 = row0 + wm*(BM/2) + m*16 + l4*4;
    #pragma unroll
    for (int n = 0; n < 4; ++n){
      const int c = col0 + wn*64 + n*16 + l15;
      #pragma unroll
      for (int j = 0; j < 4; ++j){
        const size_t idx = (size_t)(r0 + j)*N + c;
        const float v = acc[m][n][j];
        if constexpr (EPI == 1)      Cf[idx] = v + resid[idx];
        else if constexpr (EPI == 2) Cb[idx] = f2bf(v / (1.f + __expf(-v)));
        else if constexpr (EPI == 3) Cb[idx] = f2bf(v * bf2f(emul[idx]));
        else                         Cb[idx] = f2bf(v);
      }
    }
  }
}

// ====== m201-style 8-phase GEMM: C[M,N]=A[M,K]*Bt[N,K]^T, 256x256, BK=64 ======
// 2 buffers x 4 half-tile slots (Alo@0, Ahi@16K, Blo@32K, Bhi@48K); 8 phases / 2 K-tiles;
// per phase: ds_read frags -> stage ONE half-tile -> [vmcnt(4) at ph4/ph8] -> barrier ->
// lgkmcnt(0) -> setprio+16 MFMA -> barrier. Stage->read flight = 5-6 phases.
#define G8_PHASE(BUF, MH, NH, READB, SDSTOFF, SBASE, SKT, VM) do {                          \
  const char* bb_ = smem + (BUF)*65536;                                                     \
  short8 afr[4][2];                                                                         \
  _Pragma("unroll")                                                                         \
  for (int m_=0;m_<4;m_++){                                                                 \
    _Pragma("unroll")                                                                       \
    for (int k_=0;k_<2;k_++) afr[m_][k_] = *(const short8*)(bb_ + offA[(MH)*4+m_][k_]); }   \
  if (READB){                                                                               \
    _Pragma("unroll")                                                                       \
    for (int n_=0;n_<2;n_++){                                                               \
      _Pragma("unroll")                                                                     \
      for (int k_=0;k_<2;k_++) bfr[n_][k_] = *(const short8*)(bb_ + offB[(NH)*2+n_][k_]); } } \
  STG((SDSTOFF), (SBASE), (SKT));                                                           \
  if (VM) asm volatile("s_waitcnt vmcnt(4)" ::: "memory");                                  \
  __builtin_amdgcn_s_barrier();                                                             \
  asm volatile("s_waitcnt lgkmcnt(0)" ::: "memory");                                        \
  __builtin_amdgcn_sched_barrier(0);                                                        \
  __builtin_amdgcn_s_setprio(1);                                                            \
  _Pragma("unroll")                                                                         \
  for (int m_=0;m_<4;m_++){                                                                 \
    _Pragma("unroll")                                                                       \
    for (int n_=0;n_<2;n_++){                                                               \
      _Pragma("unroll")                                                                     \
      for (int k_=0;k_<2;k_++)                                                              \
        acc[(MH)*4+m_][(NH)*2+n_] = __builtin_amdgcn_mfma_f32_16x16x32_bf16(                \
            afr[m_][k_], bfr[n_][k_], acc[(MH)*4+m_][(NH)*2+n_], 0,0,0); } }                \
  __builtin_amdgcn_s_setprio(0);                                                            \
  __builtin_amdgcn_s_barrier();                                                             \
  __builtin_amdgcn_sched_barrier(0);                                                        \
} while(0)

template<int EPI>
__global__ __launch_bounds__(512, 2) void gemm8x(
    const __hip_bfloat16* __restrict__ A,
    const __hip_bfloat16* __restrict__ Bt,
    __hip_bfloat16* __restrict__ Cb,
    const __hip_bfloat16* __restrict__ emul,
    int M, int N, int K, int NTN)
{
  extern __shared__ char smem[];                 // 131072
  const int tid = threadIdx.x, lane = tid & 63, wave = tid >> 6;
  const int l15 = lane & 15, l4 = lane >> 4;
  const int wm = wave >> 2, wn = wave & 3;       // 2M x 4N waves; wave out 128x64

  const int nwg = gridDim.x;
  const int id  = blockIdx.x;
  const int swz = (id & 7) * (nwg >> 3) + (id >> 3);
  const int by = swz / NTN, bx = swz % NTN;
  const int row0 = by * 256, col0 = bx * 256;

  const __hip_bfloat16* pAlo = A  + (size_t)row0*K;
  const __hip_bfloat16* pAhi = A  + (size_t)(row0+128)*K;
  const __hip_bfloat16* pBlo = Bt + (size_t)col0*K;
  const __hip_bfloat16* pBhi = Bt + (size_t)(col0+128)*K;

  // staging: half-tile = 128 rows x 128B; chunk c: r=c>>3, s=c&7, col=(s*16)^((r&7)<<4)
  const int c0r = tid >> 3, c0s = tid & 7;
  const size_t so0 = (size_t)c0r*K + (((c0s*16) ^ ((c0r & 7) << 4)) >> 1);
  const int c1 = 512 + tid, c1r = c1 >> 3, c1s = c1 & 7;
  const size_t so1 = (size_t)c1r*K + (((c1s*16) ^ ((c1r & 7) << 4)) >> 1);
  const int do0 = tid*16, do1 = c1*16;
  auto STG = [&](int dstoff, const __hip_bfloat16* base, int kt){
    gl_lds16(base + (size_t)kt*64 + so0, smem + dstoff + do0);
    gl_lds16(base + (size_t)kt*64 + so1, smem + dstoff + do1);
  };

  // fragment read offsets (within one 64KB buffer)
  int offA[8][2], offB[4][2];
  #pragma unroll
  for (int m = 0; m < 8; ++m){
    const int row = wm*128 + m*16 + l15;
    const int part = row >> 7, rr = row & 127;
    #pragma unroll
    for (int ks = 0; ks < 2; ++ks)
      offA[m][ks] = part*16384 + rr*128 + ((ks*64 + l4*16) ^ ((rr & 7) << 4));
  }
  #pragma unroll
  for (int n = 0; n < 4; ++n){
    const int row = wn*64 + n*16 + l15;
    const int part = row >> 7, rr = row & 127;
    #pragma unroll
    for (int ks = 0; ks < 2; ++ks)
      offB[n][ks] = 32768 + part*16384 + rr*128 + ((ks*64 + l4*16) ^ ((rr & 7) << 4));
  }

  f32x4 acc[8][4] = {};
  short8 bfr[2][2];
  const int NT = K >> 6, NITER = NT >> 1;

  // prologue: buf0 <- tile0 (all 4 ht), buf1 <- {Blo,Alo} of tile1; vmcnt(4) -> buf0 ready
  STG(0,         pAlo, 0); STG(16384,       pAhi, 0);
  STG(32768,     pBlo, 0); STG(49152,       pBhi, 0);
  STG(65536+32768, pBlo, 1); STG(65536+0,   pAlo, 1);
  __builtin_amdgcn_sched_barrier(0);
  asm volatile("s_waitcnt vmcnt(4)" ::: "memory");
  __builtin_amdgcn_s_barrier();
  __builtin_amdgcn_sched_barrier(0);

  for (int i = 0; i < NITER; ++i){
    const int T0 = 2*i;
    const int s01 = T0 + 1;                       // buf1.{Ahi,Bhi} for THIS iter's T1
    const int s02 = (T0+2 < NT) ? T0+2 : 0;       // buf0 refill (next iter T0)
    const int s03 = (T0+3 < NT) ? T0+3 : 0;       // buf1.{Blo,Alo} (next iter T1)
    G8_PHASE(0, 0,0, true,  65536+16384, pAhi, s01, 0);   // ph1
    G8_PHASE(0, 1,0, false, 65536+49152, pBhi, s01, 0);   // ph2
    G8_PHASE(0, 0,1, true,  0+32768,     pBlo, s02, 0);   // ph3
    G8_PHASE(0, 1,1, false, 0+0,         pAlo, s02, 1);   // ph4 (vmcnt)
    G8_PHASE(1, 0,0, true,  0+16384,     pAhi, s02, 0);   // ph5
    G8_PHASE(1, 1,0, false, 0+49152,     pBhi, s02, 0);   // ph6
    G8_PHASE(1, 0,1, true,  65536+32768, pBlo, s03, 0);   // ph7
    G8_PHASE(1, 1,1, false, 65536+0,     pAlo, s03, 1);   // ph8 (vmcnt)
  }

  #pragma unroll
  for (int m = 0; m < 8; ++m){
    const int r0 = row0 + wm*128 + m*16 + l4*4;
    #pragma unroll
    for (int n = 0; n < 4; ++n){
      const int c = col0 + wn*64 + n*16 + l15;
      #pragma unroll
      for (int j = 0; j < 4; ++j){
        const size_t idx = (size_t)(r0 + j)*N + c;
        const float v = acc[m][n][j];
        if constexpr (EPI == 2)      Cb[idx] = f2bf(v / (1.f + __expf(-v)));
        else if constexpr (EPI == 3) Cb[idx] = f2bf(v * bf2f(emul[idx]));
        else                         Cb[idx] = f2bf(v);
      }
    }
  }
}

// ------ RoPE + pack: qkv bf16 (B,T,3C) -> Q,K (BH,T,128) bf16, Vt (BH,128,T) bf16 ------
__global__ __launch_bounds__(256) void ropepack(
    const __hip_bfloat16* __restrict__ qkv, const float* __restrict__ cosT, const float* __restrict__ sinT,
    __hip_bfloat16* __restrict__ Qo, __hip_bfloat16* __restrict__ Ko, __hip_bfloat16* __restrict__ Vo)
{
  __shared__ short vt[128][72];
  const int bh = blockIdx.y, b = bh>>4, h = bh&15;
  const int t0 = blockIdx.x*64, tid = threadIdx.x;
  const int tr = tid>>2, q4 = tid&3;
  const int tg = t0 + tr;
  const __hip_bfloat16* base = qkv + ((size_t)(b*2048 + tg))*6144 + h*128;
  const int pp0 = q4*16;
  float cs[16], sn[16];
  #pragma unroll
  for (int i=0;i<4;i++){
    float4 c4 = *(const float4*)(cosT + (size_t)tg*64 + pp0 + i*4);
    float4 s4 = *(const float4*)(sinT + (size_t)tg*64 + pp0 + i*4);
    cs[i*4+0]=c4.x; cs[i*4+1]=c4.y; cs[i*4+2]=c4.z; cs[i*4+3]=c4.w;
    sn[i*4+0]=s4.x; sn[i*4+1]=s4.y; sn[i*4+2]=s4.z; sn[i*4+3]=s4.w;
  }
  #pragma unroll
  for (int qk=0; qk<2; ++qk){
    const __hip_bfloat16* src = base + qk*2048;
    __hip_bfloat16* dst = (qk==0 ? Qo : Ko) + ((size_t)bh*2048 + tg)*128 + pp0*2;
    short8 ov[4];
    short* o = (short*)ov;
    #pragma unroll
    for (int i=0;i<4;i++){
      short8 v = *(const short8*)(src + pp0*2 + i*8);
      #pragma unroll
      for (int j=0;j<4;j++){
        float xe = sb2f(v[2*j]), xo = sb2f(v[2*j+1]);
        float c = cs[4*i+j], s = sn[4*i+j];
        o[8*i+2*j]   = bfbits(xe*c - xo*s);
        o[8*i+2*j+1] = bfbits(xe*s + xo*c);
      }
    }
    #pragma unroll
    for (int i=0;i<4;i++) *(short8*)(dst + i*8) = ov[i];
  }
  const __hip_bfloat16* vsrc = base + 4096;
  const int vc0 = q4*32;
  #pragma unroll
  for (int i=0;i<4;i++){
    short8 v = *(const short8*)(vsrc + vc0 + i*8);
    #pragma unroll
    for (int j=0;j<8;j++) vt[vc0+i*8+j][tr] = v[j];
  }
  __syncthreads();
  const int d = tid>>1, th0 = (tid&1)*32;
  __hip_bfloat16* vdst = Vo + ((size_t)bh*128 + d)*2048 + t0 + th0;
  #pragma unroll
  for (int i=0;i<4;i++)
    *(short8*)(vdst + i*8) = *(const short8*)(&vt[d][th0 + i*8]);
}

// ----- Flash attention, causal: 8 waves, KVBLK=64, LDS dbuf, ones-MFMA denominator -----
__global__ __launch_bounds__(512, 2) void attn_k(
    const __hip_bfloat16* __restrict__ Q,
    const __hip_bfloat16* __restrict__ K,
    const __hip_bfloat16* __restrict__ Vt,
    __hip_bfloat16* __restrict__ Y)
{
  extern __shared__ char lds[];
  const int bh = blockIdx.x, b = bh>>4, h = bh&15;
  const int by = blockIdx.y;
  const int qtA = 15 - 2*by, qtB = 2*by;
  const int tid = threadIdx.x, lane = tid&63, wave = tid>>6;
  const int qt = (wave < 4) ? qtA : qtB;
  const int qbase = qt*128 + (wave&3)*32;
  const int qmax = (qtA > qtB) ? qtA : qtB;
  const int nsteps = 2*qmax + 2;
  const __hip_bfloat16* Qh = Q + (size_t)bh*2048*128;
  const __hip_bfloat16* Kh = K + (size_t)bh*2048*128;
  const __hip_bfloat16* Vh = Vt + (size_t)bh*128*2048;
  char* plbase = lds + 65536 + wave*4608;
  const int l15 = lane & 15, l4 = lane >> 4;
  const int swzm = (l15 & 7) << 4;

  const int krA = tid >> 4;  const int kjA = (tid & 15) * 16;
  const size_t ksrcA = (size_t)krA*128 + ((kjA ^ ((krA & 7) << 4)) >> 1);
  const size_t ksrcB = (size_t)(krA+32)*128 + ((kjA ^ ((krA & 7) << 4)) >> 1);
  const int vrA = tid >> 3;  const int vjA = (tid & 7) * 16;
  const size_t vsrcA = (size_t)vrA*2048 + ((vjA ^ ((vrA & 7) << 4)) >> 1);
  const size_t vsrcB = (size_t)(vrA+64)*2048 + ((vjA ^ ((vrA & 7) << 4)) >> 1);
  auto STAGE = [&](int buf, int kv0){
    char* kb = lds + buf*16384;
    char* vb = lds + 32768 + buf*16384;
    gl_lds16(Kh + (size_t)kv0*128 + ksrcA, kb + tid*16);
    gl_lds16(Kh + (size_t)kv0*128 + ksrcB, kb + 8192 + tid*16);
    gl_lds16(Vh + kv0 + vsrcA, vb + tid*16);
    gl_lds16(Vh + kv0 + vsrcB, vb + 8192 + tid*16);
  };

  short8 qf[2][4];
  #pragma unroll
  for (int m=0;m<2;m++)
    #pragma unroll
    for (int kc=0;kc<4;kc++)
      qf[m][kc] = *(const short8*)(Qh + (size_t)(qbase + m*16 + l15)*128 + kc*32 + l4*8);

  short8 of;
  #pragma unroll
  for (int i=0;i<8;i++) of[i] = (l15==0) ? (short)0x3F80 : (short)0;

  f32x4 accO[2][9] = {};
  float mrow[2][4];
  #pragma unroll
  for (int m=0;m<2;m++)
    #pragma unroll
    for (int j=0;j<4;j++) mrow[m][j] = -1e30f;
  const float scale = 0.08838834764831845f;

  STAGE(0, 0);
  STAGE(1, 64);
  __builtin_amdgcn_sched_barrier(0);
  asm volatile("s_waitcnt vmcnt(4)" ::: "memory");
  __builtin_amdgcn_s_barrier();
  __builtin_amdgcn_sched_barrier(0);

  for (int s = 0; s < nsteps; ++s){
    const int kv0 = s*64;
    const char* kb = lds + (s&1)*16384;
    const char* vb = lds + 32768 + (s&1)*16384;
    if (kv0 <= qbase){
      const bool diag = (kv0 + 64 > qbase);
      const int kvrel = kv0 - qbase;
      f32x4 sc[2][4] = {};
      #pragma unroll
      for (int n=0;n<4;n++){
        short8 kf[4];
        #pragma unroll
        for (int kc=0;kc<4;kc++)
          kf[kc] = *(const short8*)(kb + (n*16 + l15)*256 + ((kc*64 + l4*16) ^ swzm));
        #pragma unroll
        for (int m=0;m<2;m++)
          #pragma unroll
          for (int kc=0;kc<4;kc++)
            sc[m][n] = __builtin_amdgcn_mfma_f32_16x16x32_bf16(qf[m][kc], kf[kc], sc[m][n], 0,0,0);
      }
      float alpha_[2][4];
      #pragma unroll
      for (int m=0;m<2;m++)
        #pragma unroll
        for (int j=0;j<4;j++){
          const int qr = 16*m + 4*l4 + j;
          float a[4];
          #pragma unroll
          for (int n=0;n<4;n++){
            a[n] = sc[m][n][j]*scale;
            if (diag && (kvrel + n*16 + l15 > qr)) a[n] = -1e30f;
          }
          float mx = fmaxf(fmaxf(a[0],a[1]), fmaxf(a[2],a[3]));
          #pragma unroll
          for (int o=1;o<16;o<<=1) mx = fmaxf(mx, __shfl_xor(mx, o));
          const float mn = fmaxf(mrow[m][j], mx);
          const float al = __expf(mrow[m][j] - mn);
          mrow[m][j] = mn;
          alpha_[m][j] = al;
          __hip_bfloat16* pr = (__hip_bfloat16*)(plbase + qr*144) + l15;
          #pragma unroll
          for (int n=0;n<4;n++) pr[n*16] = f2bf(__expf(a[n] - mn));
        }
      #pragma unroll
      for (int m=0;m<2;m++)
        #pragma unroll
        for (int db=0;db<9;db++)
          #pragma unroll
          for (int j=0;j<4;j++)
            accO[m][db][j] *= alpha_[m][j];
      asm volatile("s_waitcnt lgkmcnt(0)" ::: "memory");
      __builtin_amdgcn_sched_barrier(0);
      short8 pa[2][2];
      #pragma unroll
      for (int m=0;m<2;m++)
        #pragma unroll
        for (int ks=0;ks<2;ks++)
          pa[m][ks] = *(const short8*)(plbase + (m*16 + l15)*144 + ks*64 + l4*16);
      #pragma unroll
      for (int db=0;db<8;db++){
        #pragma unroll
        for (int ks=0;ks<2;ks++){
          short8 vf = *(const short8*)(vb + (db*16 + l15)*128 + ((ks*64 + l4*16) ^ swzm));
          #pragma unroll
          for (int m=0;m<2;m++)
            accO[m][db] = __builtin_amdgcn_mfma_f32_16x16x32_bf16(pa[m][ks], vf, accO[m][db], 0,0,0);
        }
      }
      #pragma unroll
      for (int ks=0;ks<2;ks++)
        #pragma unroll
        for (int m=0;m<2;m++)
          accO[m][8] = __builtin_amdgcn_mfma_f32_16x16x32_bf16(pa[m][ks], of, accO[m][8], 0,0,0);
    }
    __builtin_amdgcn_sched_barrier(0);
    __builtin_amdgcn_s_barrier();
    __builtin_amdgcn_sched_barrier(0);
    if (s + 2 < nsteps){
      STAGE(s&1, (s+2)*64);
      __builtin_amdgcn_sched_barrier(0);
      asm volatile("s_waitcnt vmcnt(4)" ::: "memory");
    } else {
      asm volatile("s_waitcnt vmcnt(0)" ::: "memory");
    }
    __builtin_amdgcn_s_barrier();
    __builtin_amdgcn_sched_barrier(0);
  }

  #pragma unroll
  for (int m=0;m<2;m++){
    float lr[4];
    #pragma unroll
    for (int j=0;j<4;j++) lr[j] = __shfl(accO[m][8][j], l4*16);
    #pragma unroll
    for (int db=0;db<8;db++)
      #pragma unroll
      for (int j=0;j<4;j++){
        const int tg = qbase + 16*m + 4*l4 + j;
        const int d  = 16*db + l15;
        Y[((size_t)b*2048 + tg)*2048 + h*128 + d] = f2bf(accO[m][db][j] / lr[j]);
      }
  }
}

// ---------------- launcher ----------------
extern "C" void kernel_launch(void* const* d_in, const int* in_sizes, int n_in,
                              void* d_out, int out_size, void* d_ws, size_t ws_size,
                              hipStream_t stream)
{
  const float* x    = (const float*)d_in[0];
  const float* cosT = (const float*)d_in[1];
  const float* sinT = (const float*)d_in[2];
  const float* ln1w = (const float*)d_in[3];
  const float* ln1b = (const float*)d_in[4];
  const float* ln2w = (const float*)d_in[5];
  const float* ln2b = (const float*)d_in[6];
  const float* Wqkv = (const float*)d_in[7];
  const float* Wo   = (const float*)d_in[8];
  const float* W1   = (const float*)d_in[9];
  const float* W2   = (const float*)d_in[10];
  const float* W3   = (const float*)d_in[11];
  float* out = (float*)d_out;

  if (ws_size < 150994944) return;
  char* ws = (char*)d_ws;
  __hip_bfloat16* WT    = (__hip_bfloat16*)(ws);
  __hip_bfloat16* W2T   = (__hip_bfloat16*)(ws + 33554432);
  __hip_bfloat16* WoT   = (__hip_bfloat16*)(ws + 50331648);
  __hip_bfloat16* abf   = (__hip_bfloat16*)(ws + 67108864);
  __hip_bfloat16* qkvb  = (__hip_bfloat16*)(ws + 83886080);
  __hip_bfloat16* sub   = (__hip_bfloat16*)(ws + 83886080);
  __hip_bfloat16* Qb    = (__hip_bfloat16*)(ws);
  __hip_bfloat16* Kb    = (__hip_bfloat16*)(ws + 16777216);
  __hip_bfloat16* Vtb   = (__hip_bfloat16*)(ws + 33554432);
  __hip_bfloat16* Yb    = (__hip_bfloat16*)(ws + 134217728);
  float*          x2    = out;

  hipFuncSetAttribute(reinterpret_cast<const void*>(&gemm8x<4>),
                      hipFuncAttributeMaxDynamicSharedMemorySize, 131072);
  hipFuncSetAttribute(reinterpret_cast<const void*>(&gemm8x<2>),
                      hipFuncAttributeMaxDynamicSharedMemorySize, 131072);
  hipFuncSetAttribute(reinterpret_cast<const void*>(&gemm8x<3>),
                      hipFuncAttributeMaxDynamicSharedMemorySize, 131072);
  hipFuncSetAttribute(reinterpret_cast<const void*>(&gemmp<1,128>),
                      hipFuncAttributeMaxDynamicSharedMemorySize, 98304);
  hipFuncSetAttribute(reinterpret_cast<const void*>(&attn_k),
                      hipFuncAttributeMaxDynamicSharedMemorySize, 102400);

  ln_k<<<4096,256,0,stream>>>(x, ln1w, ln1b, abf);
  wtrans<<<dim3(192,64),256,0,stream>>>(Wqkv, WT, 2048, 6144);
  gemm8x<4><<<384,512,131072,stream>>>(abf, WT, qkvb, nullptr, 4096, 6144, 2048, 24);
  ropepack<<<dim3(32,32),256,0,stream>>>(qkvb, cosT, sinT, Qb, Kb, Vtb);
  attn_k<<<dim3(32,8),512,102400,stream>>>(Qb, Kb, Vtb, Yb);
  wtrans<<<dim3(64,64),256,0,stream>>>(Wo, WoT, 2048, 2048);
  gemmp<1,128><<<256,512,98304,stream>>>(Yb, WoT, nullptr, x2, x, nullptr, 4096, 2048, 2048, 8);
  ln_k<<<4096,256,0,stream>>>(x2, ln2w, ln2b, abf);
  wtrans<<<dim3(256,64),256,0,stream>>>(W1, WT, 2048, 8192);
  gemm8x<2><<<512,512,131072,stream>>>(abf, WT, sub, nullptr, 4096, 8192, 2048, 32);
  wtrans<<<dim3(256,64),256,0,stream>>>(W2, W2T, 2048, 8192);
  gemm8x<3><<<512,512,131072,stream>>>(abf, W2T, sub, sub, 4096, 8192, 2048, 32);
  wtrans<<<dim3(64,256),256,0,stream>>>(W3, WT, 8192, 2048);
  gemmp<1,128><<<256,512,98304,stream>>>(sub, WT, nullptr, out, x2, nullptr, 4096, 2048, 8192, 8);
}

// Round 15
// 790.149 us; speedup vs baseline: 1.0315x; 1.0315x over previous
//
#include <hip/hip_runtime.h>
#include <hip/hip_bf16.h>
#include <cstdint>

#define DEVINL __device__ __forceinline__

using f32x4  = __attribute__((ext_vector_type(4))) float;
using short8 = __attribute__((ext_vector_type(8))) short;
using short4v = __attribute__((ext_vector_type(4))) short;

DEVINL float bf2f(__hip_bfloat16 h){ return __bfloat162float(h); }
DEVINL __hip_bfloat16 f2bf(float f){ return __float2bfloat16(f); }
DEVINL short bfbits(float f){ __hip_bfloat16 h = __float2bfloat16(f); short s; __builtin_memcpy(&s, &h, 2); return s; }
DEVINL float sb2f(short s){ uint32_t u = ((uint32_t)(uint16_t)s) << 16; float f; __builtin_memcpy(&f, &u, 4); return f; }

DEVINL void gl_lds16(const void* g, void* l){
  __builtin_amdgcn_global_load_lds((const __attribute__((address_space(1))) void*)g,
                                   (__attribute__((address_space(3))) void*)l, 16, 0, 0);
}

// ---------------- weight transpose + f32->bf16 cast: dst[C][R] = src[R][C] ----------------
__global__ __launch_bounds__(256) void wtrans(const float* __restrict__ src,
                                              __hip_bfloat16* __restrict__ dst,
                                              int R, int C){
  __shared__ float tile[32][33];
  const int tr0 = blockIdx.y*32, tc0 = blockIdx.x*32;
  const int t = threadIdx.x;
  const int lr = t >> 3, lc = (t & 7) * 4;
  float4 v = *(const float4*)(src + (size_t)(tr0+lr)*C + tc0 + lc);
  tile[lr][lc] = v.x; tile[lr][lc+1] = v.y; tile[lr][lc+2] = v.z; tile[lr][lc+3] = v.w;
  __syncthreads();
  short4v o;
  o[0] = bfbits(tile[lc+0][lr]);
  o[1] = bfbits(tile[lc+1][lr]);
  o[2] = bfbits(tile[lc+2][lr]);
  o[3] = bfbits(tile[lc+3][lr]);
  *(short4v*)(dst + (size_t)(tc0+lr)*R + tr0 + lc) = o;
}

// ---------------- LayerNorm (C=2048), one row per block, bf16 out ----------------
__global__ __launch_bounds__(256) void ln_k(const float* __restrict__ x,
                                            const float* __restrict__ w,
                                            const float* __restrict__ bia,
                                            __hip_bfloat16* __restrict__ out){
  const int row = blockIdx.x, t = threadIdx.x;
  const float* xr = x + (size_t)row*2048;
  float4 v0 = *(const float4*)(xr + t*4);
  float4 v1 = *(const float4*)(xr + 1024 + t*4);
  float s  = v0.x+v0.y+v0.z+v0.w + v1.x+v1.y+v1.z+v1.w;
  float ss = v0.x*v0.x+v0.y*v0.y+v0.z*v0.z+v0.w*v0.w
           + v1.x*v1.x+v1.y*v1.y+v1.z*v1.z+v1.w*v1.w;
  #pragma unroll
  for (int o=1;o<64;o<<=1){ s += __shfl_xor(s,o); ss += __shfl_xor(ss,o); }
  __shared__ float red[8];
  const int wv = t>>6, ln = t&63;
  if (ln==0){ red[wv]=s; red[4+wv]=ss; }
  __syncthreads();
  s = red[0]+red[1]+red[2]+red[3]; ss = red[4]+red[5]+red[6]+red[7];
  const float mu = s*(1.f/2048.f);
  const float inv = rsqrtf(ss*(1.f/2048.f) - mu*mu + 1e-5f);
  {
    float4 wv4 = *(const float4*)(w + t*4);
    float4 bv4 = *(const float4*)(bia + t*4);
    short4v o;
    o[0]=bfbits((v0.x-mu)*inv*wv4.x + bv4.x);
    o[1]=bfbits((v0.y-mu)*inv*wv4.y + bv4.y);
    o[2]=bfbits((v0.z-mu)*inv*wv4.z + bv4.z);
    o[3]=bfbits((v0.w-mu)*inv*wv4.w + bv4.w);
    *(short4v*)(out + (size_t)row*2048 + t*4) = o;
  }
  {
    float4 wv4 = *(const float4*)(w + 1024 + t*4);
    float4 bv4 = *(const float4*)(bia + 1024 + t*4);
    short4v o;
    o[0]=bfbits((v1.x-mu)*inv*wv4.x + bv4.x);
    o[1]=bfbits((v1.y-mu)*inv*wv4.y + bv4.y);
    o[2]=bfbits((v1.z-mu)*inv*wv4.z + bv4.z);
    o[3]=bfbits((v1.w-mu)*inv*wv4.w + bv4.w);
    *(short4v*)(out + (size_t)row*2048 + 1024 + t*4) = o;
  }
}

// ====== quad-buffered GEMM (r10-proven): C[M,N]=A[M,K]*Bt[N,K]^T, BM x 256, BK=32 ======
// EPI 4: bf16   2: silu->bf16   3: *emul->bf16 (in-place ok)   1: f32 + resid (in-place ok)
template<int EPI, int BM>
__global__ __launch_bounds__(512, 2) void gemmp(
    const __hip_bfloat16* __restrict__ A,
    const __hip_bfloat16* __restrict__ Bt,
    __hip_bfloat16* __restrict__ Cb,
    float* __restrict__ Cf,
    const float* __restrict__ resid,
    const __hip_bfloat16* __restrict__ emul,
    int M, int N, int K, int NTN)
{
  constexpr int MF    = BM/32;
  constexpr int LA    = BM/128;
  constexpr int ABY   = BM*64;
  constexpr int TILEB = ABY + 16384;
  extern __shared__ char smem[];
  const int tid = threadIdx.x, lane = tid & 63, wave = tid >> 6;
  const int l15 = lane & 15, l4 = lane >> 4;
  const int wm = wave >> 2, wn = wave & 3;

  const int nwg = gridDim.x;
  const int id  = blockIdx.x;
  const int swz = (id & 7) * (nwg >> 3) + (id >> 3);
  const int by = swz / NTN, bx = swz % NTN;
  const int row0 = by * BM, col0 = bx * 256;

  const __hip_bfloat16* srcA[LA]; int dstA[LA];
  #pragma unroll
  for (int g = 0; g < LA; ++g){
    const int c = g*512 + tid, r = c >> 2, s = c & 3;
    const int kbyte = (s*16) ^ (((r >> 1) & 3) << 4);
    srcA[g] = A + (size_t)(row0 + r)*K + (kbyte >> 1);
    dstA[g] = c*16;
  }
  const __hip_bfloat16* srcB[2]; int dstB[2];
  #pragma unroll
  for (int g = 0; g < 2; ++g){
    const int c = g*512 + tid, r = c >> 2, s = c & 3;
    const int kbyte = (s*16) ^ (((r >> 1) & 3) << 4);
    srcB[g] = Bt + (size_t)(col0 + r)*K + (kbyte >> 1);
    dstB[g] = c*16;
  }
  auto STAGE = [&](int bi, int kt){
    char* base = smem + bi*TILEB;
    #pragma unroll
    for (int g = 0; g < LA; ++g) gl_lds16(srcA[g] + kt*32, base + dstA[g]);
    #pragma unroll
    for (int g = 0; g < 2; ++g)  gl_lds16(srcB[g] + kt*32, base + ABY + dstB[g]);
  };

  const int rmask = ((l15 >> 1) & 3) << 4;
  int offA[MF], offB[4];
  #pragma unroll
  for (int m = 0; m < MF; ++m){
    const int r = wm*(BM/2) + m*16 + l15;
    offA[m] = r*64 + ((l4*16) ^ rmask);
  }
  #pragma unroll
  for (int n = 0; n < 4; ++n){
    const int r = wn*64 + n*16 + l15;
    offB[n] = r*64 + ((l4*16) ^ rmask);
  }

  f32x4 acc[MF][4] = {};
  const int NT = K >> 5;

  STAGE(0, 0); STAGE(1, 1); STAGE(2, 2);
  __builtin_amdgcn_sched_barrier(0);
  if constexpr (BM == 256) asm volatile("s_waitcnt vmcnt(8)" ::: "memory");
  else                     asm volatile("s_waitcnt vmcnt(6)" ::: "memory");
  __builtin_amdgcn_s_barrier();
  __builtin_amdgcn_sched_barrier(0);

  for (int t = 0; t < NT; ++t){
    const char* base = smem + (t & 3)*TILEB;
    if (t + 3 < NT) STAGE((t + 3) & 3, t + 3);
    short8 a[MF], b[4];
    #pragma unroll
    for (int m = 0; m < MF; ++m) a[m] = *(const short8*)(base + offA[m]);
    #pragma unroll
    for (int n = 0; n < 4; ++n)  b[n] = *(const short8*)(base + ABY + offB[n]);
    __builtin_amdgcn_s_setprio(1);
    #pragma unroll
    for (int m = 0; m < MF; ++m)
      #pragma unroll
      for (int n = 0; n < 4; ++n)
        acc[m][n] = __builtin_amdgcn_mfma_f32_16x16x32_bf16(a[m], b[n], acc[m][n], 0, 0, 0);
    __builtin_amdgcn_s_setprio(0);
    if (t + 3 < NT){
      if constexpr (BM == 256) asm volatile("s_waitcnt vmcnt(8)" ::: "memory");
      else                     asm volatile("s_waitcnt vmcnt(6)" ::: "memory");
    } else if (t + 2 < NT){
      if constexpr (BM == 256) asm volatile("s_waitcnt vmcnt(4)" ::: "memory");
      else                     asm volatile("s_waitcnt vmcnt(3)" ::: "memory");
    } else {
      asm volatile("s_waitcnt vmcnt(0)" ::: "memory");
    }
    __builtin_amdgcn_s_barrier();
    __builtin_amdgcn_sched_barrier(0);
  }

  #pragma unroll
  for (int m = 0; m < MF; ++m){
    const int r0 = row0 + wm*(BM/2) + m*16 + l4*4;
    #pragma unroll
    for (int n = 0; n < 4; ++n){
      const int c = col0 + wn*64 + n*16 + l15;
      #pragma unroll
      for (int j = 0; j < 4; ++j){
        const size_t idx = (size_t)(r0 + j)*N + c;
        const float v = acc[m][n][j];
        if constexpr (EPI == 1)      Cf[idx] = v + resid[idx];
        else if constexpr (EPI == 2) Cb[idx] = f2bf(v / (1.f + __expf(-v)));
        else if constexpr (EPI == 3) Cb[idx] = f2bf(v * bf2f(emul[idx]));
        else                         Cb[idx] = f2bf(v);
      }
    }
  }
}

// ====== fused SwiGLU GEMM: sub = silu(A*W1t^T) * (A*W2t^T), tile 256M x 128N (r13) ======
__global__ __launch_bounds__(512, 2) void gemmf(
    const __hip_bfloat16* __restrict__ A,
    const __hip_bfloat16* __restrict__ B1t,
    const __hip_bfloat16* __restrict__ B2t,
    __hip_bfloat16* __restrict__ Cb,
    int M, int N, int K, int NTN)
{
  constexpr int ABY   = 16384;
  constexpr int TILEB = ABY + 16384;
  extern __shared__ char smem[];
  const int tid = threadIdx.x, lane = tid & 63, wave = tid >> 6;
  const int l15 = lane & 15, l4 = lane >> 4;
  const int wm = wave >> 2, wn = wave & 3;

  const int nwg = gridDim.x;
  const int id  = blockIdx.x;
  const int swz = (id & 7) * (nwg >> 3) + (id >> 3);
  const int by = swz / NTN, bx = swz % NTN;
  const int row0 = by * 256, col0 = bx * 128;

  const __hip_bfloat16* srcA[2]; int dstA[2];
  #pragma unroll
  for (int g = 0; g < 2; ++g){
    const int c = g*512 + tid, r = c >> 2, s = c & 3;
    const int kbyte = (s*16) ^ (((r >> 1) & 3) << 4);
    srcA[g] = A + (size_t)(row0 + r)*K + (kbyte >> 1);
    dstA[g] = c*16;
  }
  const __hip_bfloat16* srcB[2]; int dstB[2];
  #pragma unroll
  for (int g = 0; g < 2; ++g){
    const int c = g*512 + tid, r = c >> 2, s = c & 3;
    const int kbyte = (s*16) ^ (((r >> 1) & 3) << 4);
    const __hip_bfloat16* base = (r < 128) ? (B1t + (size_t)(col0 + r)*K)
                                           : (B2t + (size_t)(col0 + r - 128)*K);
    srcB[g] = base + (kbyte >> 1);
    dstB[g] = c*16;
  }
  auto STAGE = [&](int bi, int kt){
    char* base = smem + bi*TILEB;
    #pragma unroll
    for (int g = 0; g < 2; ++g) gl_lds16(srcA[g] + kt*32, base + dstA[g]);
    #pragma unroll
    for (int g = 0; g < 2; ++g) gl_lds16(srcB[g] + kt*32, base + ABY + dstB[g]);
  };

  const int rmask = ((l15 >> 1) & 3) << 4;
  int offA[8], offB[2][2];
  #pragma unroll
  for (int m = 0; m < 8; ++m){
    const int r = wm*128 + m*16 + l15;
    offA[m] = r*64 + ((l4*16) ^ rmask);
  }
  #pragma unroll
  for (int g = 0; g < 2; ++g)
    #pragma unroll
    for (int nf = 0; nf < 2; ++nf){
      const int r = g*128 + wn*32 + nf*16 + l15;
      offB[g][nf] = r*64 + ((l4*16) ^ rmask);
    }

  f32x4 acc[8][2][2] = {};
  const int NT = K >> 5;

  STAGE(0, 0); STAGE(1, 1); STAGE(2, 2);
  __builtin_amdgcn_sched_barrier(0);
  asm volatile("s_waitcnt vmcnt(8)" ::: "memory");
  __builtin_amdgcn_s_barrier();
  __builtin_amdgcn_sched_barrier(0);

  for (int t = 0; t < NT; ++t){
    const char* base = smem + (t & 3)*TILEB;
    if (t + 3 < NT) STAGE((t + 3) & 3, t + 3);
    short8 a[8], b[2][2];
    #pragma unroll
    for (int m = 0; m < 8; ++m) a[m] = *(const short8*)(base + offA[m]);
    #pragma unroll
    for (int g = 0; g < 2; ++g)
      #pragma unroll
      for (int nf = 0; nf < 2; ++nf) b[g][nf] = *(const short8*)(base + ABY + offB[g][nf]);
    __builtin_amdgcn_s_setprio(1);
    #pragma unroll
    for (int m = 0; m < 8; ++m)
      #pragma unroll
      for (int g = 0; g < 2; ++g)
        #pragma unroll
        for (int nf = 0; nf < 2; ++nf)
          acc[m][g][nf] = __builtin_amdgcn_mfma_f32_16x16x32_bf16(a[m], b[g][nf], acc[m][g][nf], 0, 0, 0);
    __builtin_amdgcn_s_setprio(0);
    if (t + 3 < NT)      asm volatile("s_waitcnt vmcnt(8)" ::: "memory");
    else if (t + 2 < NT) asm volatile("s_waitcnt vmcnt(4)" ::: "memory");
    else                 asm volatile("s_waitcnt vmcnt(0)" ::: "memory");
    __builtin_amdgcn_s_barrier();
    __builtin_amdgcn_sched_barrier(0);
  }

  #pragma unroll
  for (int m = 0; m < 8; ++m){
    const int r0 = row0 + wm*128 + m*16 + l4*4;
    #pragma unroll
    for (int nf = 0; nf < 2; ++nf){
      const int c = col0 + wn*32 + nf*16 + l15;
      #pragma unroll
      for (int j = 0; j < 4; ++j){
        const float h1 = acc[m][0][nf][j];
        const float h2 = acc[m][1][nf][j];
        Cb[(size_t)(r0 + j)*N + c] = f2bf((h1 / (1.f + __expf(-h1))) * h2);
      }
    }
  }
}

// ------ RoPE + pack: qkv bf16 (B,T,3C) -> Q,K (BH,T,128) bf16, Vt (BH,128,T) bf16 ------
__global__ __launch_bounds__(256) void ropepack(
    const __hip_bfloat16* __restrict__ qkv, const float* __restrict__ cosT, const float* __restrict__ sinT,
    __hip_bfloat16* __restrict__ Qo, __hip_bfloat16* __restrict__ Ko, __hip_bfloat16* __restrict__ Vo)
{
  __shared__ short vt[128][72];
  const int bh = blockIdx.y, b = bh>>4, h = bh&15;
  const int t0 = blockIdx.x*64, tid = threadIdx.x;
  const int tr = tid>>2, q4 = tid&3;
  const int tg = t0 + tr;
  const __hip_bfloat16* base = qkv + ((size_t)(b*2048 + tg))*6144 + h*128;
  const int pp0 = q4*16;
  float cs[16], sn[16];
  #pragma unroll
  for (int i=0;i<4;i++){
    float4 c4 = *(const float4*)(cosT + (size_t)tg*64 + pp0 + i*4);
    float4 s4 = *(const float4*)(sinT + (size_t)tg*64 + pp0 + i*4);
    cs[i*4+0]=c4.x; cs[i*4+1]=c4.y; cs[i*4+2]=c4.z; cs[i*4+3]=c4.w;
    sn[i*4+0]=s4.x; sn[i*4+1]=s4.y; sn[i*4+2]=s4.z; sn[i*4+3]=s4.w;
  }
  #pragma unroll
  for (int qk=0; qk<2; ++qk){
    const __hip_bfloat16* src = base + qk*2048;
    __hip_bfloat16* dst = (qk==0 ? Qo : Ko) + ((size_t)bh*2048 + tg)*128 + pp0*2;
    short8 ov[4];
    short* o = (short*)ov;
    #pragma unroll
    for (int i=0;i<4;i++){
      short8 v = *(const short8*)(src + pp0*2 + i*8);
      #pragma unroll
      for (int j=0;j<4;j++){
        float xe = sb2f(v[2*j]), xo = sb2f(v[2*j+1]);
        float c = cs[4*i+j], s = sn[4*i+j];
        o[8*i+2*j]   = bfbits(xe*c - xo*s);
        o[8*i+2*j+1] = bfbits(xe*s + xo*c);
      }
    }
    #pragma unroll
    for (int i=0;i<4;i++) *(short8*)(dst + i*8) = ov[i];
  }
  const __hip_bfloat16* vsrc = base + 4096;
  const int vc0 = q4*32;
  #pragma unroll
  for (int i=0;i<4;i++){
    short8 v = *(const short8*)(vsrc + vc0 + i*8);
    #pragma unroll
    for (int j=0;j<8;j++) vt[vc0+i*8+j][tr] = v[j];
  }
  __syncthreads();
  const int d = tid>>1, th0 = (tid&1)*32;
  __hip_bfloat16* vdst = Vo + ((size_t)bh*128 + d)*2048 + t0 + th0;
  #pragma unroll
  for (int i=0;i<4;i++)
    *(short8*)(vdst + i*8) = *(const short8*)(&vt[d][th0 + i*8]);
}

// ----- Flash attention, causal: 4 waves/block, 1 supertile, 2 blocks/CU, KVBLK=64 -----
// LDS 66KB: K dbuf 2x16KB @0, V single 16KB @32768 (T14 early-issue), P 4x4608 @49152.
// Grid (32 bh, 16 by): qt = by<8 ? 15-2by : 2(by-8) -> heavy+light co-resident per CU.
__global__ __launch_bounds__(256, 2) void attn_k(
    const __hip_bfloat16* __restrict__ Q,
    const __hip_bfloat16* __restrict__ K,
    const __hip_bfloat16* __restrict__ Vt,
    __hip_bfloat16* __restrict__ Y)
{
  extern __shared__ char lds[];
  const int bh = blockIdx.x, b = bh>>4, h = bh&15;
  const int by = blockIdx.y;
  const int qt = (by < 8) ? (15 - 2*by) : (2*(by - 8));
  const int tid = threadIdx.x, lane = tid&63, wave = tid>>6;
  const int qbase = qt*128 + wave*32;
  const int nsteps = 2*qt + 2;
  const __hip_bfloat16* Qh = Q + (size_t)bh*2048*128;
  const __hip_bfloat16* Kh = K + (size_t)bh*2048*128;
  const __hip_bfloat16* Vh = Vt + (size_t)bh*128*2048;
  char* plbase = lds + 49152 + wave*4608;          // 32 rows x 144B
  const int l15 = lane & 15, l4 = lane >> 4;
  const int swzm = (l15 & 7) << 4;

  // staging: 4 chunks/thread. K tile 64 keys x 256B (16 chunks/row); V tile 128 d x 128B (8/row)
  size_t ksrc[4], vsrc[4];
  int cdst[4];
  #pragma unroll
  for (int i = 0; i < 4; ++i){
    const int c = i*256 + tid;
    const int kr = c >> 4, kslot = c & 15;
    const int kcolb = (kslot*16) ^ ((kr & 7) << 4);
    ksrc[i] = (size_t)kr*128 + (kcolb >> 1);
    const int vr = c >> 3, vslot = c & 7;
    const int vcolb = (vslot*16) ^ ((vr & 7) << 4);
    vsrc[i] = (size_t)vr*2048 + (vcolb >> 1);
    cdst[i] = c*16;
  }
  auto STK = [&](int buf, int kv0){
    #pragma unroll
    for (int i = 0; i < 4; ++i)
      gl_lds16(Kh + (size_t)kv0*128 + ksrc[i], lds + buf*16384 + cdst[i]);
  };
  auto STV = [&](int kv0){
    #pragma unroll
    for (int i = 0; i < 4; ++i)
      gl_lds16(Vh + kv0 + vsrc[i], lds + 32768 + cdst[i]);
  };

  short8 qf[2][4];
  #pragma unroll
  for (int m=0;m<2;m++)
    #pragma unroll
    for (int kc=0;kc<4;kc++)
      qf[m][kc] = *(const short8*)(Qh + (size_t)(qbase + m*16 + l15)*128 + kc*32 + l4*8);

  short8 of;                                       // ones B-fragment: col 0 = 1.0
  #pragma unroll
  for (int i=0;i<8;i++) of[i] = (l15==0) ? (short)0x3F80 : (short)0;

  f32x4 accO[2][9] = {};
  float mrow[2][4];
  #pragma unroll
  for (int m=0;m<2;m++)
    #pragma unroll
    for (int j=0;j<4;j++) mrow[m][j] = -1e30f;
  const float scale = 0.08838834764831845f;

  STK(0, 0);
  __builtin_amdgcn_sched_barrier(0);
  asm volatile("s_waitcnt vmcnt(0)" ::: "memory");
  __builtin_amdgcn_s_barrier();
  __builtin_amdgcn_sched_barrier(0);

  for (int s = 0; s < nsteps; ++s){
    const int kv0 = s*64;
    const char* kb = lds + (s&1)*16384;
    const char* vb = lds + 32768;
    const bool act = (kv0 <= qbase);
    const bool pfK = (s + 1 < nsteps);
    // T14: issue V(s) now (consumed after QK^T+softmax); prefetch K(s+1)
    STV(kv0);
    if (pfK) STK((s+1)&1, kv0 + 64);
    __builtin_amdgcn_sched_barrier(0);
    float alpha_[2][4];
    if (act){
      const bool diag = (kv0 + 64 > qbase);
      const int kvrel = kv0 - qbase;
      f32x4 sc[2][4] = {};
      #pragma unroll
      for (int n=0;n<4;n++){
        short8 kf[4];
        #pragma unroll
        for (int kc=0;kc<4;kc++)
          kf[kc] = *(const short8*)(kb + (n*16 + l15)*256 + ((kc*64 + l4*16) ^ swzm));
        #pragma unroll
        for (int m=0;m<2;m++)
          #pragma unroll
          for (int kc=0;kc<4;kc++)
            sc[m][n] = __builtin_amdgcn_mfma_f32_16x16x32_bf16(qf[m][kc], kf[kc], sc[m][n], 0,0,0);
      }
      #pragma unroll
      for (int m=0;m<2;m++)
        #pragma unroll
        for (int j=0;j<4;j++){
          const int qr = 16*m + 4*l4 + j;
          float a[4];
          #pragma unroll
          for (int n=0;n<4;n++){
            a[n] = sc[m][n][j]*scale;
            if (diag && (kvrel + n*16 + l15 > qr)) a[n] = -1e30f;
          }
          float mx = fmaxf(fmaxf(a[0],a[1]), fmaxf(a[2],a[3]));
          #pragma unroll
          for (int o=1;o<16;o<<=1) mx = fmaxf(mx, __shfl_xor(mx, o));
          const float mn = fmaxf(mrow[m][j], mx);
          const float al = __expf(mrow[m][j] - mn);
          mrow[m][j] = mn;
          alpha_[m][j] = al;
          __hip_bfloat16* pr = (__hip_bfloat16*)(plbase + qr*144) + l15;
          #pragma unroll
          for (int n=0;n<4;n++) pr[n*16] = f2bf(__expf(a[n] - mn));
        }
      #pragma unroll
      for (int m=0;m<2;m++)
        #pragma unroll
        for (int db=0;db<9;db++)
          #pragma unroll
          for (int j=0;j<4;j++)
            accO[m][db][j] *= alpha_[m][j];
      asm volatile("s_waitcnt lgkmcnt(0)" ::: "memory");
      __builtin_amdgcn_sched_barrier(0);
    }
    // V(s) resident (own 4 loads done; K's 4 may remain in flight), then all waves synced
    if (pfK) asm volatile("s_waitcnt vmcnt(4)" ::: "memory");
    else     asm volatile("s_waitcnt vmcnt(0)" ::: "memory");
    __builtin_amdgcn_s_barrier();
    __builtin_amdgcn_sched_barrier(0);
    if (act){
      short8 pa[2][2];
      #pragma unroll
      for (int m=0;m<2;m++)
        #pragma unroll
        for (int ks=0;ks<2;ks++)
          pa[m][ks] = *(const short8*)(plbase + (m*16 + l15)*144 + ks*64 + l4*16);
      #pragma unroll
      for (int db=0;db<8;db++){
        #pragma unroll
        for (int ks=0;ks<2;ks++){
          short8 vf = *(const short8*)(vb + (db*16 + l15)*128 + ((ks*64 + l4*16) ^ swzm));
          #pragma unroll
          for (int m=0;m<2;m++)
            accO[m][db] = __builtin_amdgcn_mfma_f32_16x16x32_bf16(pa[m][ks], vf, accO[m][db], 0,0,0);
        }
      }
      #pragma unroll
      for (int ks=0;ks<2;ks++)
        #pragma unroll
        for (int m=0;m<2;m++)
          accO[m][8] = __builtin_amdgcn_mfma_f32_16x16x32_bf16(pa[m][ks], of, accO[m][8], 0,0,0);
    }
    __builtin_amdgcn_sched_barrier(0);
    // end of step: K(s+1) landed everywhere; V buffer free for next step
    asm volatile("s_waitcnt vmcnt(0)" ::: "memory");
    __builtin_amdgcn_s_barrier();
    __builtin_amdgcn_sched_barrier(0);
  }

  #pragma unroll
  for (int m=0;m<2;m++){
    float lr[4];
    #pragma unroll
    for (int j=0;j<4;j++) lr[j] = __shfl(accO[m][8][j], l4*16);
    #pragma unroll
    for (int db=0;db<8;db++)
      #pragma unroll
      for (int j=0;j<4;j++){
        const int tg = qbase + 16*m + 4*l4 + j;
        const int d  = 16*db + l15;
        Y[((size_t)b*2048 + tg)*2048 + h*128 + d] = f2bf(accO[m][db][j] / lr[j]);
      }
  }
}

// ---------------- launcher ----------------
extern "C" void kernel_launch(void* const* d_in, const int* in_sizes, int n_in,
                              void* d_out, int out_size, void* d_ws, size_t ws_size,
                              hipStream_t stream)
{
  const float* x    = (const float*)d_in[0];
  const float* cosT = (const float*)d_in[1];
  const float* sinT = (const float*)d_in[2];
  const float* ln1w = (const float*)d_in[3];
  const float* ln1b = (const float*)d_in[4];
  const float* ln2w = (const float*)d_in[5];
  const float* ln2b = (const float*)d_in[6];
  const float* Wqkv = (const float*)d_in[7];
  const float* Wo   = (const float*)d_in[8];
  const float* W1   = (const float*)d_in[9];
  const float* W2   = (const float*)d_in[10];
  const float* W3   = (const float*)d_in[11];
  float* out = (float*)d_out;

  if (ws_size < 150994944) return;
  char* ws = (char*)d_ws;
  __hip_bfloat16* WT    = (__hip_bfloat16*)(ws);
  __hip_bfloat16* W2T   = (__hip_bfloat16*)(ws + 33554432);
  __hip_bfloat16* WoT   = (__hip_bfloat16*)(ws + 50331648);
  __hip_bfloat16* abf   = (__hip_bfloat16*)(ws + 67108864);
  __hip_bfloat16* qkvb  = (__hip_bfloat16*)(ws + 83886080);
  __hip_bfloat16* sub   = (__hip_bfloat16*)(ws + 83886080);
  __hip_bfloat16* Qb    = (__hip_bfloat16*)(ws);
  __hip_bfloat16* Kb    = (__hip_bfloat16*)(ws + 16777216);
  __hip_bfloat16* Vtb   = (__hip_bfloat16*)(ws + 33554432);
  __hip_bfloat16* Yb    = (__hip_bfloat16*)(ws + 134217728);
  float*          x2    = out;

  hipFuncSetAttribute(reinterpret_cast<const void*>(&gemmp<4,128>),
                      hipFuncAttributeMaxDynamicSharedMemorySize, 98304);
  hipFuncSetAttribute(reinterpret_cast<const void*>(&gemmp<1,128>),
                      hipFuncAttributeMaxDynamicSharedMemorySize, 98304);
  hipFuncSetAttribute(reinterpret_cast<const void*>(&gemmf),
                      hipFuncAttributeMaxDynamicSharedMemorySize, 131072);
  hipFuncSetAttribute(reinterpret_cast<const void*>(&attn_k),
                      hipFuncAttributeMaxDynamicSharedMemorySize, 67584);

  ln_k<<<4096,256,0,stream>>>(x, ln1w, ln1b, abf);
  wtrans<<<dim3(192,64),256,0,stream>>>(Wqkv, WT, 2048, 6144);
  gemmp<4,128><<<768,512,98304,stream>>>(abf, WT, qkvb, nullptr, nullptr, nullptr, 4096, 6144, 2048, 24);
  ropepack<<<dim3(32,32),256,0,stream>>>(qkvb, cosT, sinT, Qb, Kb, Vtb);
  attn_k<<<dim3(32,16),256,67584,stream>>>(Qb, Kb, Vtb, Yb);
  wtrans<<<dim3(64,64),256,0,stream>>>(Wo, WoT, 2048, 2048);
  gemmp<1,128><<<256,512,98304,stream>>>(Yb, WoT, nullptr, x2, x, nullptr, 4096, 2048, 2048, 8);
  ln_k<<<4096,256,0,stream>>>(x2, ln2w, ln2b, abf);
  wtrans<<<dim3(256,64),256,0,stream>>>(W1, WT, 2048, 8192);
  wtrans<<<dim3(256,64),256,0,stream>>>(W2, W2T, 2048, 8192);
  gemmf<<<1024,512,131072,stream>>>(abf, WT, W2T, sub, 4096, 8192, 2048, 64);
  wtrans<<<dim3(64,256),256,0,stream>>>(W3, WT, 8192, 2048);
  gemmp<1,128><<<256,512,98304,stream>>>(sub, WT, nullptr, out, x2, nullptr, 4096, 2048, 8192, 8);
}